// Round 1
// baseline (113.706 us; speedup 1.0000x reference)
//
#include <hip/hip_runtime.h>

// Problem dims (fixed by reference setup_inputs)
#define NB 4
#define LB 512
#define DB 1024
#define PB 768
#define NBINS 64
#define LEN_KEEP 128          // int(512 * (1 - 0.75))
#define EPSL 1e-19f

// ---------------------------------------------------------------------------
// 1) global min/max of img_pat, deterministic two-pass (no atomics)
// ---------------------------------------------------------------------------
__global__ void minmax_partial(const float* __restrict__ v, int n,
                               float* __restrict__ bmin, float* __restrict__ bmax) {
    __shared__ float smin[256], smax[256];
    int tid = threadIdx.x;
    float mn = 1e30f, mx = -1e30f;
    for (int i = blockIdx.x * 256 + tid; i < n; i += 256 * gridDim.x) {
        float x = v[i];
        mn = fminf(mn, x);
        mx = fmaxf(mx, x);
    }
    smin[tid] = mn; smax[tid] = mx;
    __syncthreads();
    for (int s = 128; s > 0; s >>= 1) {
        if (tid < s) {
            smin[tid] = fminf(smin[tid], smin[tid + s]);
            smax[tid] = fmaxf(smax[tid], smax[tid + s]);
        }
        __syncthreads();
    }
    if (tid == 0) { bmin[blockIdx.x] = smin[0]; bmax[blockIdx.x] = smax[0]; }
}

__global__ void minmax_final(const float* __restrict__ bmin, const float* __restrict__ bmax,
                             float* __restrict__ mm) {
    __shared__ float smin[256], smax[256];
    int tid = threadIdx.x;
    smin[tid] = bmin[tid]; smax[tid] = bmax[tid];
    __syncthreads();
    for (int s = 128; s > 0; s >>= 1) {
        if (tid < s) {
            smin[tid] = fminf(smin[tid], smin[tid + s]);
            smax[tid] = fmaxf(smax[tid], smax[tid + s]);
        }
        __syncthreads();
    }
    if (tid == 0) { mm[0] = smin[0]; mm[1] = smax[0]; }
}

// ---------------------------------------------------------------------------
// 2) KDE entropy per token. One block per (n,l): 2048 blocks x 256 threads.
//    Thread (b = tid&63, c = tid>>6) accumulates bin b over value chunk c.
// ---------------------------------------------------------------------------
__global__ void entropy_kernel(const float* __restrict__ img,
                               const float* __restrict__ mm,
                               float* __restrict__ ent) {
    __shared__ float snv[PB];
    __shared__ float red[4][NBINS];
    int t = blockIdx.x;          // token index 0..2047
    int tid = threadIdx.x;
    float vmin = mm[0];
    float inv = 1.0f / (mm[1] - vmin);
    const float* row = img + (size_t)t * PB;
    for (int i = tid; i < PB; i += 256) snv[i] = (row[i] - vmin) * inv;
    __syncthreads();

    int b = tid & 63;
    int c = tid >> 6;
    float binv = (float)b * (1.0f / 63.0f);
    float acc = 0.0f;
    int base = c * (PB / 4);
#pragma unroll 8
    for (int i = 0; i < PB / 4; ++i) {
        float d = snv[base + i] - binv;
        // exp(-0.5 * (d/0.01)^2) = exp(-5000 * d^2)
        acc += __expf(d * d * -5000.0f);
    }
    red[c][b] = acc;
    __syncthreads();

    if (tid < 64) {   // exactly one wavefront
        float pdf = (red[0][b] + red[1][b] + red[2][b] + red[3][b]) * (1.0f / (float)PB);
        float s = pdf;
        for (int m = 1; m < 64; m <<= 1) s += __shfl_xor(s, m, 64);
        float p = pdf / (s + EPSL) + EPSL;
        float term = p * __logf(p);
        for (int m = 1; m < 64; m <<= 1) term += __shfl_xor(term, m, 64);
        if (tid == 0) ent[t] = -term;
    }
}

// ---------------------------------------------------------------------------
// 3) per-row stable argsort (bitonic on (key, idx) lexicographic), then write
//    mask + ids_restore (as float) and stash ids_keep for the gather.
// ---------------------------------------------------------------------------
__global__ void sort_kernel(const float* __restrict__ ent,
                            int* __restrict__ ids_keep,
                            float* __restrict__ out_mask,
                            float* __restrict__ out_restore) {
    __shared__ float key[LB];
    __shared__ int   idx[LB];
    int n = blockIdx.x, tid = threadIdx.x;
    for (int i = tid; i < LB; i += 256) { key[i] = ent[n * LB + i]; idx[i] = i; }
    __syncthreads();
    for (int k = 2; k <= LB; k <<= 1) {
        for (int j = k >> 1; j >= 1; j >>= 1) {
            for (int i = tid; i < LB; i += 256) {
                int ixj = i ^ j;
                if (ixj > i) {
                    bool up = ((i & k) == 0);
                    float ka = key[i], kb = key[ixj];
                    int   ia = idx[i], ib = idx[ixj];
                    bool agtb = (ka > kb) || (ka == kb && ia > ib);
                    if (agtb == up) {
                        key[i] = kb; key[ixj] = ka;
                        idx[i] = ib; idx[ixj] = ia;
                    }
                }
            }
            __syncthreads();
        }
    }
    for (int i = tid; i < LB; i += 256) {
        int id = idx[i];                       // ids_shuffle[i]
        out_restore[n * LB + id] = (float)i;   // ids_restore[id] = rank
        out_mask[n * LB + id] = (i < LEN_KEEP) ? 0.0f : 1.0f;
        if (i < LEN_KEEP) ids_keep[n * LEN_KEEP + i] = id;
    }
}

// ---------------------------------------------------------------------------
// 4) gather kept rows of x: block (i, n), 256 threads x float4 = 1024 floats
// ---------------------------------------------------------------------------
__global__ void gather_kernel(const float* __restrict__ x,
                              const int* __restrict__ ids_keep,
                              float* __restrict__ out) {
    int i = blockIdx.x;    // 0..127
    int n = blockIdx.y;    // 0..3
    int row = ids_keep[n * LEN_KEEP + i];
    const float4* src = (const float4*)(x + ((size_t)(n * LB + row)) * DB);
    float4* dst = (float4*)(out + ((size_t)(n * LEN_KEEP + i)) * DB);
    dst[threadIdx.x] = src[threadIdx.x];
}

extern "C" void kernel_launch(void* const* d_in, const int* in_sizes, int n_in,
                              void* d_out, int out_size, void* d_ws, size_t ws_size,
                              hipStream_t stream) {
    const float* x   = (const float*)d_in[0];   // (4,512,1024)
    const float* img = (const float*)d_in[1];   // (4,512,768)

    float* out       = (float*)d_out;
    float* out_x     = out;                              // 4*128*1024 = 524288
    float* out_mask  = out + (size_t)NB * LEN_KEEP * DB; // 4*512 = 2048
    float* out_rest  = out_mask + NB * LB;               // 4*512 = 2048

    float* ws   = (float*)d_ws;
    float* mm   = ws;            // [0]=vmin [1]=vmax
    float* bmin = ws + 2;        // 256
    float* bmax = ws + 258;      // 256
    float* ent  = ws + 514;      // 2048
    int*   ids  = (int*)(ws + 514 + NB * LB);  // 512 ints

    minmax_partial<<<256, 256, 0, stream>>>(img, NB * LB * PB, bmin, bmax);
    minmax_final<<<1, 256, 0, stream>>>(bmin, bmax, mm);
    entropy_kernel<<<NB * LB, 256, 0, stream>>>(img, mm, ent);
    sort_kernel<<<NB, 256, 0, stream>>>(ent, ids, out_mask, out_rest);
    gather_kernel<<<dim3(LEN_KEEP, NB), 256, 0, stream>>>(x, ids, out_x);
}

// Round 2
// 96.293 us; speedup vs baseline: 1.1808x; 1.1808x over previous
//
#include <hip/hip_runtime.h>

#define NB 4
#define LB 512
#define DB 1024
#define PB 768
#define NBINS 64
#define LEN_KEEP 128          // int(512 * (1 - 0.75))
#define EPSL 1e-19f

#if defined(__has_builtin)
#if __has_builtin(__builtin_amdgcn_exp2f)
#define HAVE_EXP2 1
#endif
#endif

__device__ __forceinline__ float fast_exp2(float x) {
#ifdef HAVE_EXP2
    return __builtin_amdgcn_exp2f(x);   // raw v_exp_f32
#else
    return __expf(x * 0.69314718055994530942f);
#endif
}

// ---------------------------------------------------------------------------
// 1) global min/max of img_pat, deterministic two-pass, float4 loads
//    1,572,864 floats = 393,216 float4 = 256 blocks x 256 threads x 6
// ---------------------------------------------------------------------------
__global__ void minmax_partial(const float4* __restrict__ v,
                               float* __restrict__ bmin, float* __restrict__ bmax) {
    __shared__ float smin[256], smax[256];
    int tid = threadIdx.x;
    int base = blockIdx.x * 256 + tid;
    float mn = 1e30f, mx = -1e30f;
#pragma unroll
    for (int k = 0; k < 6; ++k) {
        float4 x = v[base + k * 65536];
        mn = fminf(mn, fminf(fminf(x.x, x.y), fminf(x.z, x.w)));
        mx = fmaxf(mx, fmaxf(fmaxf(x.x, x.y), fmaxf(x.z, x.w)));
    }
    smin[tid] = mn; smax[tid] = mx;
    __syncthreads();
    for (int s = 128; s > 0; s >>= 1) {
        if (tid < s) {
            smin[tid] = fminf(smin[tid], smin[tid + s]);
            smax[tid] = fmaxf(smax[tid], smax[tid + s]);
        }
        __syncthreads();
    }
    if (tid == 0) { bmin[blockIdx.x] = smin[0]; bmax[blockIdx.x] = smax[0]; }
}

__global__ void minmax_final(const float* __restrict__ bmin, const float* __restrict__ bmax,
                             float* __restrict__ mm) {
    __shared__ float smin[256], smax[256];
    int tid = threadIdx.x;
    smin[tid] = bmin[tid]; smax[tid] = bmax[tid];
    __syncthreads();
    for (int s = 128; s > 0; s >>= 1) {
        if (tid < s) {
            smin[tid] = fminf(smin[tid], smin[tid + s]);
            smax[tid] = fmaxf(smax[tid], smax[tid + s]);
        }
        __syncthreads();
    }
    if (tid == 0) { mm[0] = smin[0]; mm[1] = smax[0]; }
}

// ---------------------------------------------------------------------------
// 2) KDE entropy per token — LDS-free main loop.
//    exp(-5000*(nv-bv)^2) = 2^( -K*(v-m_b)^2 ),  K = 5000*log2(e)*inv^2,
//    m_b = vmin + bv*range  (per-lane register constant, lane = bin).
//    One block per token: 4 waves, each wave handles a 192-value chunk.
// ---------------------------------------------------------------------------
__global__ void entropy_kernel(const float* __restrict__ img,
                               const float* __restrict__ mm,
                               float* __restrict__ ent) {
    int t = blockIdx.x;          // token 0..2047
    int tid = threadIdx.x;
    int lane = tid & 63;         // bin
    int c = tid >> 6;            // value chunk
    float vmin = mm[0], vmax = mm[1];
    float rng = vmax - vmin;
    float inv = 1.0f / rng;
    float negK = -7213.4755859375f * inv * inv;   // -(5000*log2 e)*inv^2
    float bv = (float)lane * (1.0f / 63.0f);
    float mb = vmin + bv * rng;

    const float4* row = (const float4*)(img + (size_t)t * PB + c * (PB / 4));
    float a0 = 0.f, a1 = 0.f, a2 = 0.f, a3 = 0.f;
#pragma unroll 4
    for (int i = 0; i < PB / 16; ++i) {   // 48 uniform float4 loads
        float4 v = row[i];
        float d0 = v.x - mb, d1 = v.y - mb, d2 = v.z - mb, d3 = v.w - mb;
        a0 += fast_exp2(d0 * d0 * negK);
        a1 += fast_exp2(d1 * d1 * negK);
        a2 += fast_exp2(d2 * d2 * negK);
        a3 += fast_exp2(d3 * d3 * negK);
    }
    float acc = (a0 + a1) + (a2 + a3);

    __shared__ float red[4][NBINS];
    red[c][lane] = acc;
    __syncthreads();

    if (tid < 64) {   // one wavefront finishes
        float pdf = (red[0][lane] + red[1][lane] + red[2][lane] + red[3][lane])
                    * (1.0f / (float)PB);
        float s = pdf;
        for (int m = 1; m < 64; m <<= 1) s += __shfl_xor(s, m, 64);
        float p = pdf / (s + EPSL) + EPSL;
        float term = p * __logf(p);
        for (int m = 1; m < 64; m <<= 1) term += __shfl_xor(term, m, 64);
        if (tid == 0) ent[t] = -term;
    }
}

// ---------------------------------------------------------------------------
// 3) rank-by-counting (replaces bitonic sort; exact stable-argsort semantics)
//    rank(i) = #{ j : (key_j, j) < (key_i, i) }  via u64 composite.
//    Entropy > 0 so float bit pattern is order-monotonic.
//    2048 elements -> 8 blocks x 256 threads; row uniform per block.
// ---------------------------------------------------------------------------
__global__ void rank_kernel(const float* __restrict__ ent,
                            int* __restrict__ ids_keep,
                            float* __restrict__ out_mask,
                            float* __restrict__ out_restore) {
    int e = blockIdx.x * 256 + threadIdx.x;   // 0..2047
    int n = e >> 9;                           // row (uniform in block)
    int i = e & 511;                          // element in row
    const float* row = ent + n * LB;
    unsigned long long ci =
        ((unsigned long long)__float_as_uint(row[i]) << 32) | (unsigned int)i;
    int r = 0;
#pragma unroll 8
    for (int j = 0; j < LB; ++j) {            // row[j] uniform -> scalar load
        unsigned long long cj =
            ((unsigned long long)__float_as_uint(row[j]) << 32) | (unsigned int)j;
        r += (cj < ci) ? 1 : 0;
    }
    out_restore[e] = (float)r;
    out_mask[e] = (r < LEN_KEEP) ? 0.0f : 1.0f;
    if (r < LEN_KEEP) ids_keep[n * LEN_KEEP + r] = i;
}

// ---------------------------------------------------------------------------
// 4) gather kept rows of x: block (i, n), 256 threads x float4 = 1024 floats
// ---------------------------------------------------------------------------
__global__ void gather_kernel(const float* __restrict__ x,
                              const int* __restrict__ ids_keep,
                              float* __restrict__ out) {
    int i = blockIdx.x;    // 0..127
    int n = blockIdx.y;    // 0..3
    int row = ids_keep[n * LEN_KEEP + i];
    const float4* src = (const float4*)(x + ((size_t)(n * LB + row)) * DB);
    float4* dst = (float4*)(out + ((size_t)(n * LEN_KEEP + i)) * DB);
    dst[threadIdx.x] = src[threadIdx.x];
}

extern "C" void kernel_launch(void* const* d_in, const int* in_sizes, int n_in,
                              void* d_out, int out_size, void* d_ws, size_t ws_size,
                              hipStream_t stream) {
    const float* x   = (const float*)d_in[0];   // (4,512,1024)
    const float* img = (const float*)d_in[1];   // (4,512,768)

    float* out       = (float*)d_out;
    float* out_x     = out;                              // 4*128*1024
    float* out_mask  = out + (size_t)NB * LEN_KEEP * DB; // 4*512
    float* out_rest  = out_mask + NB * LB;               // 4*512

    float* ws   = (float*)d_ws;
    float* mm   = ws;            // [0]=vmin [1]=vmax
    float* bmin = ws + 2;        // 256
    float* bmax = ws + 258;      // 256
    float* ent  = ws + 514;      // 2048
    int*   ids  = (int*)(ws + 514 + NB * LB);  // 512 ints

    minmax_partial<<<256, 256, 0, stream>>>((const float4*)img, bmin, bmax);
    minmax_final<<<1, 256, 0, stream>>>(bmin, bmax, mm);
    entropy_kernel<<<NB * LB, 256, 0, stream>>>(img, mm, ent);
    rank_kernel<<<8, 256, 0, stream>>>(ent, ids, out_mask, out_rest);
    gather_kernel<<<dim3(LEN_KEEP, NB), 256, 0, stream>>>(x, ids, out_x);
}